// Round 4
// baseline (2227.800 us; speedup 1.0000x reference)
//
#include <hip/hip_runtime.h>
#include <hip/hip_bf16.h>

// ---- problem constants ----
#define BB_ 32      // batch
#define PP_ 196     // pixels
#define DD_ 2048    // encoder dim
#define HH_ 512     // hidden
#define VV_ 30000   // vocab
#define TT_ 19      // timesteps
#define KX_ 2560    // H + D
#define KG_ 3072    // H + D + H
#define NTV_ 1875   // VV_/16 n-tiles for out GEMM
#define NBOUT_ 469  // blocks for out GEMM part (469*4 waves >= 1875)

typedef __attribute__((ext_vector_type(8))) short bf16x8;   // 8 bf16 (4 VGPRs)
typedef __attribute__((ext_vector_type(4))) float f32x4;

__device__ __forceinline__ unsigned short bf16b(float x) {
    __hip_bfloat16 h = __float2bfloat16(x);
    unsigned short u; __builtin_memcpy(&u, &h, 2); return u;
}
__device__ __forceinline__ float b2f(unsigned short u) {
    return __uint_as_float((unsigned int)u << 16);
}
__device__ __forceinline__ float sigf(float x) { return 1.f / (1.f + __expf(-x)); }
// tanh(x) = 1 - 2/(e^{2x}+1); correct limits at +/-inf
__device__ __forceinline__ float ftanh(float x) {
    return 1.f - 2.f / (__expf(2.f * x) + 1.f);
}

// ---------------- fused conversion kernel (one launch) ----------------

__device__ __forceinline__ void d_cvt8(int bid, int tid,
        const float* __restrict__ src, unsigned short* __restrict__ dst) {
    size_t i0 = ((size_t)bid * 256 + tid) * 8;
    float4 a = *(const float4*)&src[i0];
    float4 b = *(const float4*)&src[i0 + 4];
    bf16x8 v;
    v[0]=bf16b(a.x); v[1]=bf16b(a.y); v[2]=bf16b(a.z); v[3]=bf16b(a.w);
    v[4]=bf16b(b.x); v[5]=bf16b(b.y); v[6]=bf16b(b.z); v[7]=bf16b(b.w);
    *(bf16x8*)&dst[i0] = v;
}

// Pre-fragment row-major f32 W[K][N] into per-lane MFMA B-fragment order.
// Fragment f = ((nt*(K/32)+ks)*64+lane); lane=16g+r holds B[ks*32+8g+i][nt*16+r].
__device__ __forceinline__ void d_nsplit(int bid, int tid,
        const float* __restrict__ A, int NA, const float* __restrict__ Bp, int NB,
        int K, unsigned short* __restrict__ dst) {
    int gid = bid * 256 + tid;
    int lane = gid & 63, rest = gid >> 6;
    int KS = K >> 5;
    int ks = rest % KS, nt = rest / KS;
    int g = lane >> 4, r = lane & 15;
    int k0 = ks * 32 + g * 8;
    int n = nt * 16 + r;
    const float* src; int stride, col;
    if (n < NA) { src = A; stride = NA; col = n; }
    else        { src = Bp; stride = NB; col = n - NA; }
    bf16x8 v;
#pragma unroll
    for (int i = 0; i < 8; i++)
        v[i] = bf16b(src[(size_t)(k0 + i) * stride + col]);
    *(bf16x8*)&dst[(size_t)gid * 8] = v;
}

__device__ __forceinline__ void d_ksplit(int bid, int tid,
        const float* __restrict__ A, int KA, const float* __restrict__ Bp,
        int K, int N, unsigned short* __restrict__ dst) {
    int gid = bid * 256 + tid;
    int lane = gid & 63, rest = gid >> 6;
    int KS = K >> 5;
    int ks = rest % KS, nt = rest / KS;
    int g = lane >> 4, r = lane & 15;
    int k0 = ks * 32 + g * 8;
    int n = nt * 16 + r;
    bf16x8 v;
#pragma unroll
    for (int i = 0; i < 8; i++) {
        int k = k0 + i;
        const float* src = (k < KA) ? &A[(size_t)k * N] : &Bp[(size_t)(k - KA) * N];
        v[i] = bf16b(src[n]);
    }
    *(bf16x8*)&dst[(size_t)gid * 8] = v;
}

// block ranges: img 6272 | wout 7500 | wai 512 | whf 640 | wgf 3072 | wif 1024
__global__ __launch_bounds__(256) void k_cvt_all(
        const float* __restrict__ img, unsigned short* __restrict__ imgb,
        const float* __restrict__ Wout, unsigned short* __restrict__ wof,
        const float* __restrict__ Wai, unsigned short* __restrict__ waf,
        const float* __restrict__ Wah, const float* __restrict__ Wfb,
        unsigned short* __restrict__ whf,
        const float* __restrict__ Wih, const float* __restrict__ Whh,
        unsigned short* __restrict__ wgf,
        const float* __restrict__ Winh, const float* __restrict__ Winc,
        unsigned short* __restrict__ wif) {
    int b = blockIdx.x, t = threadIdx.x;
    if (b < 6272)       d_cvt8(b, t, img, imgb);
    else if (b < 13772) d_nsplit(b - 6272, t, Wout, VV_, Wout, 0, HH_, wof);
    else if (b < 14284) d_nsplit(b - 13772, t, Wai, HH_, Wai, 0, DD_, waf);
    else if (b < 14924) d_nsplit(b - 14284, t, Wah, HH_, Wfb, DD_, HH_, whf);
    else if (b < 17996) d_ksplit(b - 14924, t, Wih, KX_, Whh, KG_, 2048, wgf);
    else                d_nsplit(b - 17996, t, Winh, HH_, Winc, HH_, DD_, wif);
}

// ---------------- precompute ----------------

// mean-pool img (fp32 in) -> avg bf16 [32][2048]; block per batch
__global__ __launch_bounds__(256) void k_meanpool(const float* __restrict__ img,
                                                  unsigned short* __restrict__ avgb) {
    int b = blockIdx.x, tid = threadIdx.x;
    int d0 = tid * 8;
    const float* p = img + (size_t)b * PP_ * DD_ + d0;
    float s[8] = {};
    for (int i = 0; i < PP_; i++) {
        float4 a = *(const float4*)&p[(size_t)i * DD_];
        float4 c = *(const float4*)&p[(size_t)i * DD_ + 4];
        s[0]+=a.x; s[1]+=a.y; s[2]+=a.z; s[3]+=a.w;
        s[4]+=c.x; s[5]+=c.y; s[6]+=c.z; s[7]+=c.w;
    }
    bf16x8 v;
#pragma unroll
    for (int i = 0; i < 8; i++) v[i] = bf16b(s[i] * (1.0f / PP_));
    *(bf16x8*)&avgb[b * DD_ + d0] = v;
}

// h0/c0 = tanh(avg @ [Winh|Winc] + b) via MFMA; M=32,K=2048,N=1024
__global__ __launch_bounds__(256) void k_init_mfma(const unsigned short* __restrict__ avgb,
        const unsigned short* __restrict__ wif, const float* __restrict__ binh,
        const float* __restrict__ binc, float* __restrict__ c,
        unsigned short* __restrict__ hb) {
    int wid = blockIdx.x * 4 + (threadIdx.x >> 6);   // 0..63 n-tiles
    int lane = threadIdx.x & 63;
    int g = lane >> 4, r = lane & 15;
    f32x4 acc[2] = {};
    const unsigned short* a_base = avgb + (size_t)r * DD_ + g * 8;
#pragma unroll 4
    for (int ks = 0; ks < DD_ / 32; ks++) {
        bf16x8 a0 = *(const bf16x8*)(a_base + ks * 32);
        bf16x8 a1 = *(const bf16x8*)(a_base + 16 * DD_ + ks * 32);
        bf16x8 bf = *(const bf16x8*)(wif + ((size_t)(wid * 64 + ks) * 64 + lane) * 8);
        acc[0] = __builtin_amdgcn_mfma_f32_16x16x32_bf16(a0, bf, acc[0], 0, 0, 0);
        acc[1] = __builtin_amdgcn_mfma_f32_16x16x32_bf16(a1, bf, acc[1], 0, 0, 0);
    }
    int n = wid * 16 + r;
#pragma unroll
    for (int a = 0; a < 2; a++)
#pragma unroll
        for (int j = 0; j < 4; j++) {
            int m = 16 * a + 4 * g + j;
            float v = ftanh(acc[a][j] + ((n < HH_) ? binh[n] : binc[n - HH_]));
            if (n < HH_) hb[m * HH_ + n] = bf16b(v);
            else c[m * HH_ + (n - HH_)] = v;
        }
}

// att_img(bf16) = img @ W_att_img + b : [6272,2048]x[2048,512]
__global__ __launch_bounds__(256) void k_attimg_mfma(const unsigned short* __restrict__ imgb,
        const unsigned short* __restrict__ waf, const float* __restrict__ bias,
        unsigned short* __restrict__ attb) {
    int wid = blockIdx.x * 4 + (threadIdx.x >> 6);   // 0..3135
    int lane = threadIdx.x & 63;
    int g = lane >> 4, r = lane & 15;
    int mblk = wid >> 4, nblk = wid & 15;
    int m0 = mblk * 32, nt0 = nblk * 2;
    f32x4 acc[2][2] = {};
    const unsigned short* a_base = imgb + (size_t)(m0 + r) * DD_ + g * 8;
#pragma unroll 4
    for (int ks = 0; ks < DD_ / 32; ks++) {
        bf16x8 a0 = *(const bf16x8*)(a_base + ks * 32);
        bf16x8 a1 = *(const bf16x8*)(a_base + 16 * DD_ + ks * 32);
        bf16x8 b0 = *(const bf16x8*)(waf + ((size_t)((nt0 + 0) * 64 + ks) * 64 + lane) * 8);
        bf16x8 b1 = *(const bf16x8*)(waf + ((size_t)((nt0 + 1) * 64 + ks) * 64 + lane) * 8);
        acc[0][0] = __builtin_amdgcn_mfma_f32_16x16x32_bf16(a0, b0, acc[0][0], 0, 0, 0);
        acc[0][1] = __builtin_amdgcn_mfma_f32_16x16x32_bf16(a0, b1, acc[0][1], 0, 0, 0);
        acc[1][0] = __builtin_amdgcn_mfma_f32_16x16x32_bf16(a1, b0, acc[1][0], 0, 0, 0);
        acc[1][1] = __builtin_amdgcn_mfma_f32_16x16x32_bf16(a1, b1, acc[1][1], 0, 0, 0);
    }
#pragma unroll
    for (int mi = 0; mi < 2; mi++)
#pragma unroll
        for (int ni = 0; ni < 2; ni++) {
            int n = (nt0 + ni) * 16 + r;
            float bn = bias[n];
#pragma unroll
            for (int j = 0; j < 4; j++) {
                int m = m0 + 16 * mi + 4 * g + j;
                attb[(size_t)m * HH_ + n] = bf16b(acc[mi][ni][j] + bn);
            }
        }
}

// ---------------- per-step kernels ----------------

// [hWatt | gate] = h @ [Wah | Wfb] (+bias, sigmoid on gate); wid = n-tile
__device__ __forceinline__ void hmats_body(int wid, int lane,
        const unsigned short* __restrict__ hb, const unsigned short* __restrict__ whf,
        const float* __restrict__ bah, const float* __restrict__ bfb,
        float* __restrict__ hWatt, float* __restrict__ gate) {
    int g = lane >> 4, r = lane & 15;
    f32x4 acc[2] = {};
    const unsigned short* a_base = hb + (size_t)r * HH_ + g * 8;
#pragma unroll
    for (int ks = 0; ks < HH_ / 32; ks++) {
        bf16x8 a0 = *(const bf16x8*)(a_base + ks * 32);
        bf16x8 a1 = *(const bf16x8*)(a_base + 16 * HH_ + ks * 32);
        bf16x8 bf = *(const bf16x8*)(whf + ((size_t)(wid * 16 + ks) * 64 + lane) * 8);
        acc[0] = __builtin_amdgcn_mfma_f32_16x16x32_bf16(a0, bf, acc[0], 0, 0, 0);
        acc[1] = __builtin_amdgcn_mfma_f32_16x16x32_bf16(a1, bf, acc[1], 0, 0, 0);
    }
    int n = wid * 16 + r;
#pragma unroll
    for (int a = 0; a < 2; a++)
#pragma unroll
        for (int j = 0; j < 4; j++) {
            int m = 16 * a + 4 * g + j;
            float v = acc[a][j];
            if (n < HH_) hWatt[m * HH_ + n] = v + bah[n];
            else gate[m * DD_ + (n - HH_)] = sigf(v + bfb[n - HH_]);
        }
}

__global__ __launch_bounds__(256) void k_hmats_mfma(const unsigned short* __restrict__ hb,
        const unsigned short* __restrict__ whf, const float* __restrict__ bah,
        const float* __restrict__ bfb, float* __restrict__ hWatt, float* __restrict__ gate) {
    int wid = blockIdx.x * 4 + (threadIdx.x >> 6);
    hmats_body(wid, threadIdx.x & 63, hb, whf, bah, bfb, hWatt, gate);
}

// step1: energy + softmax + context + x assembly. grid (B, 2) x 256
__global__ __launch_bounds__(256) void k_step1(const unsigned short* __restrict__ attb,
        const unsigned short* __restrict__ imgb, const float* __restrict__ hWatt,
        const float* __restrict__ gate, const float* __restrict__ Emb,
        const int* __restrict__ captions, const float* __restrict__ v_att,
        const float* __restrict__ b_v, int t, unsigned short* __restrict__ xhb,
        const unsigned short* __restrict__ hb, float* __restrict__ alpha_out) {
    __shared__ float e_lds[PP_];
    __shared__ float sa[PP_];
    __shared__ float red[256];
    const int b = blockIdx.x, dc = blockIdx.y, tid = threadIdx.x;
    const int wv = tid >> 6, lane = tid & 63;
    // --- energy: wave wv computes rows [wv*49, wv*49+49) ---
    const float* hw = hWatt + (size_t)b * HH_ + lane * 8;
    float hw8[8], vv8[8];
    {
        float4 h0 = *(const float4*)&hw[0];
        float4 h1 = *(const float4*)&hw[4];
        const float* vp = v_att + lane * 8;
        float4 v0 = *(const float4*)&vp[0];
        float4 v1 = *(const float4*)&vp[4];
        hw8[0]=h0.x; hw8[1]=h0.y; hw8[2]=h0.z; hw8[3]=h0.w;
        hw8[4]=h1.x; hw8[5]=h1.y; hw8[6]=h1.z; hw8[7]=h1.w;
        vv8[0]=v0.x; vv8[1]=v0.y; vv8[2]=v0.z; vv8[3]=v0.w;
        vv8[4]=v1.x; vv8[5]=v1.y; vv8[6]=v1.z; vv8[7]=v1.w;
    }
    float bv0 = b_v[0];
    const unsigned short* ab = attb + (size_t)b * PP_ * HH_ + lane * 8;
    for (int i = 0; i < 49; i++) {
        int p = wv * 49 + i;
        bf16x8 av = *(const bf16x8*)(ab + (size_t)p * HH_);
        float acc = 0.f;
#pragma unroll
        for (int j = 0; j < 8; j++)
            acc += vv8[j] * ftanh(b2f((unsigned short)av[j]) + hw8[j]);
        for (int off = 32; off > 0; off >>= 1) acc += __shfl_down(acc, off);
        if (lane == 0) e_lds[p] = acc + bv0;
    }
    __syncthreads();
    // --- softmax over 196 (all 256 threads) ---
    float ev = (tid < PP_) ? e_lds[tid] : -1e30f;
    red[tid] = ev;
    __syncthreads();
    for (int s = 128; s > 0; s >>= 1) {
        if (tid < s) red[tid] = fmaxf(red[tid], red[tid + s]);
        __syncthreads();
    }
    float mx = red[0];
    __syncthreads();
    float pv = (tid < PP_) ? __expf(ev - mx) : 0.f;
    red[tid] = pv;
    __syncthreads();
    for (int s = 128; s > 0; s >>= 1) {
        if (tid < s) red[tid] += red[tid + s];
        __syncthreads();
    }
    float inv = 1.f / red[0];
    if (tid < PP_) sa[tid] = pv * inv;
    __syncthreads();
    // --- context: this block handles 1024 d (4 per thread) ---
    int d0 = dc * 1024 + tid * 4;
    const unsigned short* ib = imgb + (size_t)b * PP_ * DD_ + d0;
    float a0 = 0.f, a1 = 0.f, a2 = 0.f, a3 = 0.f;
#pragma unroll 4
    for (int p = 0; p < PP_; p++) {
        uint2 v = *(const uint2*)&ib[(size_t)p * DD_];
        float s = sa[p];
        a0 += s * __uint_as_float(v.x << 16);
        a1 += s * __uint_as_float(v.x & 0xffff0000u);
        a2 += s * __uint_as_float(v.y << 16);
        a3 += s * __uint_as_float(v.y & 0xffff0000u);
    }
    float4 gv = *(const float4*)&gate[b * DD_ + d0];
    unsigned int u01 = (unsigned int)bf16b(gv.x * a0) | ((unsigned int)bf16b(gv.y * a1) << 16);
    unsigned int u23 = (unsigned int)bf16b(gv.z * a2) | ((unsigned int)bf16b(gv.w * a3) << 16);
    *(uint2*)&xhb[b * KG_ + HH_ + d0] = make_uint2(u01, u23);
    if (dc == 0) {
        if (tid < PP_) alpha_out[((size_t)b * TT_ + t) * PP_ + tid] = sa[tid];
        if (tid < 128) {
            // embedding -> xh[0:512)
            int tok = captions[b * 20 + t];
            float4 evec = *(const float4*)&Emb[(size_t)tok * HH_ + tid * 4];
            unsigned int e01 = (unsigned int)bf16b(evec.x) | ((unsigned int)bf16b(evec.y) << 16);
            unsigned int e23 = (unsigned int)bf16b(evec.z) | ((unsigned int)bf16b(evec.w) << 16);
            *(uint2*)&xhb[b * KG_ + tid * 4] = make_uint2(e01, e23);
        } else {
            // h -> xh[2560:3072)   (safe: step1 ordered before step2)
            int i = tid - 128;
            *(uint2*)&xhb[b * KG_ + KX_ + i * 4] = *(const uint2*)&hb[b * HH_ + i * 4];
        }
    }
}

// step2: gates GEMM (x@[Wih;Whh]) + LSTM pointwise. 32 blocks x 1024 threads.
// wave w: quadrant q=w&3, k-chunk kc=w>>2 (24 of 96 ks). LDS reduce.
__global__ __launch_bounds__(1024) void k_gateslstm(const unsigned short* __restrict__ xhb,
        const unsigned short* __restrict__ wgf, const float* __restrict__ bih,
        const float* __restrict__ bhh, float* __restrict__ c,
        unsigned short* __restrict__ hb) {
    __shared__ float part[16][BB_][16];
    __shared__ float gsum[4][BB_][16];
    const int tid = threadIdx.x;
    const int w = tid >> 6, lane = tid & 63;
    const int q = w & 3, kc = w >> 2;
    const int g = lane >> 4, r = lane & 15;
    const int jb = blockIdx.x;               // 0..31
    const int nt = q * 32 + jb;
    f32x4 acc[2] = {};
    const unsigned short* a_base = xhb + (size_t)r * KG_ + g * 8;
#pragma unroll 4
    for (int i = 0; i < 24; i++) {
        int ks = kc * 24 + i;
        bf16x8 a0 = *(const bf16x8*)(a_base + ks * 32);
        bf16x8 a1 = *(const bf16x8*)(a_base + 16 * KG_ + ks * 32);
        bf16x8 bf = *(const bf16x8*)(wgf + ((size_t)(nt * 96 + ks) * 64 + lane) * 8);
        acc[0] = __builtin_amdgcn_mfma_f32_16x16x32_bf16(a0, bf, acc[0], 0, 0, 0);
        acc[1] = __builtin_amdgcn_mfma_f32_16x16x32_bf16(a1, bf, acc[1], 0, 0, 0);
    }
#pragma unroll
    for (int a = 0; a < 2; a++)
#pragma unroll
        for (int j = 0; j < 4; j++)
            part[w][16 * a + 4 * g + j][r] = acc[a][j];
    __syncthreads();
    {   // reduce 4 k-chunks: 1024 threads -> (q, m, 2 j's)
        int qq = tid >> 8, s2 = tid & 255;
        int m = s2 >> 3, j0 = (s2 & 7) * 2;
#pragma unroll
        for (int jj = 0; jj < 2; jj++) {
            int jc = j0 + jj;
            gsum[qq][m][jc] = part[qq][m][jc] + part[4 + qq][m][jc]
                            + part[8 + qq][m][jc] + part[12 + qq][m][jc];
        }
    }
    __syncthreads();
    if (tid < 512) {
        int m = tid >> 4, jc = tid & 15;
        int jg = jb * 16 + jc;
        float gi = gsum[0][m][jc] + bih[jg] + bhh[jg];
        float gf = gsum[1][m][jc] + bih[HH_ + jg] + bhh[HH_ + jg];
        float gg = gsum[2][m][jc] + bih[2 * HH_ + jg] + bhh[2 * HH_ + jg];
        float go = gsum[3][m][jc] + bih[3 * HH_ + jg] + bhh[3 * HH_ + jg];
        int ci = m * HH_ + jg;
        float cn = sigf(gf) * c[ci] + sigf(gi) * ftanh(gg);
        float hn = sigf(go) * ftanh(cn);
        c[ci] = cn;
        hb[ci] = bf16b(hn);
    }
}

// step3: blocks [0,469) -> preds = h@W_out + b ; [469,509) -> hWatt/gate (next step)
__global__ __launch_bounds__(256) void k_out_hmats(const unsigned short* __restrict__ hb,
        const unsigned short* __restrict__ wof, const float* __restrict__ bout,
        const unsigned short* __restrict__ whf, const float* __restrict__ bah,
        const float* __restrict__ bfb, float* __restrict__ preds,
        float* __restrict__ hWatt, float* __restrict__ gate, int t) {
    int lane = threadIdx.x & 63;
    int wv = threadIdx.x >> 6;
    if (blockIdx.x >= NBOUT_) {
        int wid = (blockIdx.x - NBOUT_) * 4 + wv;   // 0..159
        hmats_body(wid, lane, hb, whf, bah, bfb, hWatt, gate);
        return;
    }
    int nt = blockIdx.x * 4 + wv;
    if (nt >= NTV_) return;
    int g = lane >> 4, r = lane & 15;
    f32x4 acc[2] = {};
    const unsigned short* a_base = hb + (size_t)r * HH_ + g * 8;
#pragma unroll
    for (int ks = 0; ks < HH_ / 32; ks++) {
        bf16x8 a0 = *(const bf16x8*)(a_base + ks * 32);
        bf16x8 a1 = *(const bf16x8*)(a_base + 16 * HH_ + ks * 32);
        bf16x8 bf = *(const bf16x8*)(wof + ((size_t)(nt * 16 + ks) * 64 + lane) * 8);
        acc[0] = __builtin_amdgcn_mfma_f32_16x16x32_bf16(a0, bf, acc[0], 0, 0, 0);
        acc[1] = __builtin_amdgcn_mfma_f32_16x16x32_bf16(a1, bf, acc[1], 0, 0, 0);
    }
    int n = nt * 16 + r;
    float bn = bout[n];
#pragma unroll
    for (int a = 0; a < 2; a++)
#pragma unroll
        for (int j = 0; j < 4; j++) {
            int m = 16 * a + 4 * g + j;
            preds[((size_t)m * TT_ + t) * VV_ + n] = acc[a][j] + bn;
        }
}

// ---------------- launcher ----------------

extern "C" void kernel_launch(void* const* d_in, const int* in_sizes, int n_in,
                              void* d_out, int out_size, void* d_ws, size_t ws_size,
                              hipStream_t stream) {
    const float* img     = (const float*)d_in[0];
    const int*   caps    = (const int*)d_in[1];
    const float* Wih     = (const float*)d_in[2];
    const float* Whh     = (const float*)d_in[3];
    const float* bih     = (const float*)d_in[4];
    const float* bhh     = (const float*)d_in[5];
    const float* Winh    = (const float*)d_in[6];
    const float* binh    = (const float*)d_in[7];
    const float* Winc    = (const float*)d_in[8];
    const float* binc    = (const float*)d_in[9];
    const float* Wfb     = (const float*)d_in[10];
    const float* bfb     = (const float*)d_in[11];
    const float* Wout    = (const float*)d_in[12];
    const float* bout    = (const float*)d_in[13];
    const float* Wai     = (const float*)d_in[14];
    const float* bai     = (const float*)d_in[15];
    const float* Wah     = (const float*)d_in[16];
    const float* bah     = (const float*)d_in[17];
    const float* v_att   = (const float*)d_in[18];
    const float* b_v     = (const float*)d_in[19];
    const float* Emb     = (const float*)d_in[20];

    float* preds  = (float*)d_out;                               // [B,T,V]
    float* alphas = (float*)d_out + (size_t)BB_ * TT_ * VV_;     // [B,T,P]

    // ---- workspace layout (256B aligned) ----
    char* w = (char*)d_ws;
    size_t off = 0;
    auto alloc = [&](size_t bytes) {
        char* p = w + off;
        off += (bytes + 255) & ~(size_t)255;
        return p;
    };
    unsigned short* imgb = (unsigned short*)alloc((size_t)BB_ * PP_ * DD_ * 2); // 25.7MB
    unsigned short* wof  = (unsigned short*)alloc((size_t)HH_ * VV_ * 2);       // 30.7MB
    unsigned short* wgf  = (unsigned short*)alloc((size_t)KG_ * 2048 * 2);      // 12.6MB
    unsigned short* waf  = (unsigned short*)alloc((size_t)DD_ * HH_ * 2);       // 2.1MB
    unsigned short* whf  = (unsigned short*)alloc((size_t)HH_ * KX_ * 2);       // 2.6MB
    unsigned short* wif  = (unsigned short*)alloc((size_t)DD_ * 1024 * 2);      // 4.2MB
    unsigned short* attb = (unsigned short*)alloc((size_t)BB_ * PP_ * HH_ * 2); // 6.4MB
    unsigned short* avgb = (unsigned short*)alloc((size_t)BB_ * DD_ * 2);
    float* c       = (float*)alloc((size_t)BB_ * HH_ * 4);
    float* hWatt   = (float*)alloc((size_t)BB_ * HH_ * 4);
    float* gate    = (float*)alloc((size_t)BB_ * DD_ * 4);
    unsigned short* hb  = (unsigned short*)alloc((size_t)BB_ * HH_ * 2);
    unsigned short* xhb = (unsigned short*)alloc((size_t)BB_ * KG_ * 2);
    (void)ws_size;

    // ---- one-time conversions / precompute ----
    k_cvt_all<<<19020, 256, 0, stream>>>(img, imgb, Wout, wof, Wai, waf,
                                         Wah, Wfb, whf, Wih, Whh, wgf,
                                         Winh, Winc, wif);
    k_meanpool<<<BB_, 256, 0, stream>>>(img, avgb);
    k_init_mfma<<<16, 256, 0, stream>>>(avgb, wif, binh, binc, c, hb);
    k_attimg_mfma<<<784, 256, 0, stream>>>(imgb, waf, bai, attb);
    k_hmats_mfma<<<40, 256, 0, stream>>>(hb, whf, bah, bfb, hWatt, gate);

    // ---- timestep loop (3 kernels/step) ----
    for (int t = 0; t < TT_; t++) {
        k_step1<<<dim3(BB_, 2), 256, 0, stream>>>(attb, imgb, hWatt, gate, Emb,
                                                  caps, v_att, b_v, t, xhb, hb, alphas);
        k_gateslstm<<<BB_, 1024, 0, stream>>>(xhb, wgf, bih, bhh, c, hb);
        k_out_hmats<<<509, 256, 0, stream>>>(hb, wof, bout, whf, bah, bfb,
                                             preds, hWatt, gate, t);
    }
}